// Round 20
// baseline (99.518 us; speedup 1.0000x reference)
//
#include <hip/hip_runtime.h>
#include <hip/hip_fp16.h>
#include <math.h>

#define BATCH   32
#define N_BEADS 16384
#define BEAD_SIZE 16
#define N_ATOMS 100000
#define INV_SQRT2 0.70710678118654752440f
#define SCAN_BLK 256

typedef float v4f __attribute__((ext_vector_type(4)));  // native vec for nontemporal

// ---------- zero counts ----------
__global__ void __launch_bounds__(256)
zero_kernel(int* __restrict__ p, int n)
{
    int i = blockIdx.x * 256 + threadIdx.x;
    if (i < n) p[i] = 0;
}

// ---------- countrec: histogram + rec1[m]={slot,w0,w1,w2}
//            + recM2[m]={2cs, 2s^2, scal} (m-order, sequential) ----------
__global__ void __launch_bounds__(256)
countrec_kernel(const int* __restrict__ atom_idx,
                const int* __restrict__ slot_idx,
                const float* __restrict__ W,
                const float* __restrict__ ang,
                const float* __restrict__ scal,
                int* __restrict__ counts,
                float4* __restrict__ rec1,
                float4* __restrict__ recM2, int M)
{
    int m = blockIdx.x * blockDim.x + threadIdx.x;
    if (m >= M) return;
    int a = atom_idx[m];
    atomicAdd(&counts[a], 1);
    int slot = slot_idx[m];
    int h = slot >> 4, l = slot & 15;
    float w0 = W[(0 * N_BEADS + h) * BEAD_SIZE + l];
    float w1 = W[(1 * N_BEADS + h) * BEAD_SIZE + l];
    float w2 = W[(2 * N_BEADS + h) * BEAD_SIZE + l];
    rec1[m] = make_float4(__int_as_float(slot), w0, w1, w2);
    float sa, ca;
    __sincosf(ang[m], &sa, &ca);
    recM2[m] = make_float4(2.f * ca * sa, 2.f * sa * sa, scal[a], 0.f);
}

__global__ void __launch_bounds__(SCAN_BLK)
scan1_kernel(const int* __restrict__ counts, int* __restrict__ off,
             int* __restrict__ bsum, int n)
{
    __shared__ int s[SCAN_BLK];
    int i = blockIdx.x * SCAN_BLK + threadIdx.x;
    int c = (i < n) ? counts[i] : 0;
    s[threadIdx.x] = c;
    __syncthreads();
    int v = c;
    for (int d = 1; d < SCAN_BLK; d <<= 1) {
        int t = (threadIdx.x >= d) ? s[threadIdx.x - d] : 0;
        __syncthreads();
        v += t;
        s[threadIdx.x] = v;
        __syncthreads();
    }
    if (i < n) off[i] = v - c;
    if (threadIdx.x == SCAN_BLK - 1) bsum[blockIdx.x] = v;
}

// finalize offsets; cursor2 seeded with off; rec_a = {cnt, off, 0, 0}
__global__ void __launch_bounds__(256)
scan3_kernel(int* __restrict__ off, const int* __restrict__ bsum,
             const int* __restrict__ counts,
             int* __restrict__ cursor2, float4* __restrict__ rec_a, int n)
{
    __shared__ int red[256];
    int j = blockIdx.x;
    int partial = 0;
    for (int i = threadIdx.x; i < j; i += 256) partial += bsum[i];
    red[threadIdx.x] = partial;
    __syncthreads();
    for (int d = 128; d > 0; d >>= 1) {
        if ((int)threadIdx.x < d) red[threadIdx.x] += red[threadIdx.x + d];
        __syncthreads();
    }
    int bpref = red[0];
    int i = j * 256 + threadIdx.x;
    if (i >= n) return;
    int o = off[i] + bpref;
    off[i] = o;
    cursor2[i] = o;
    rec_a[i] = make_float4(__int_as_float(counts[i]), __int_as_float(o),
                           0.f, 0.f);
}

// fill3: the ONE random scatter — csr_m[pos]=m (cursor2 pre-seeded with off)
__global__ void __launch_bounds__(256)
fill3_kernel(const int* __restrict__ atom_idx,
             int* __restrict__ cursor2, int* __restrict__ csr_m, int M)
{
    int m = blockIdx.x * blockDim.x + threadIdx.x;
    if (m >= M) return;
    int pos = atomicAdd(&cursor2[atom_idx[m]], 1);
    csr_m[pos] = m;
}

// ---------- pass 1a: contributions ONLY — zero LDS, zero barriers ----------
// grid (nchunk, 8): bg covers b in [4bg, 4bg+4). Monotone-h gathers; direct
// coalesced 8B half4 stores. Waves run fully unsynchronized -> latency overlaps.
__global__ void __launch_bounds__(256)
contrib16_kernel(const float4* __restrict__ rec1,
                 const float4* __restrict__ recM2,
                 const float* __restrict__ p1,
                 const float* __restrict__ p2,
                 const float* __restrict__ P,
                 uint2* __restrict__ cM16,      // (B, M) half4, m-order
                 int M)
{
    int bg = blockIdx.y;             // 0..7
    int m = blockIdx.x * 256 + threadIdx.x;
    if (m >= M) return;
    int b0 = bg * 4;

    float4 r1 = rec1[m];
    float4 r2 = recM2[m];
    int h = __float_as_int(r1.x) >> 4;
    float A = r2.x, Bc = r2.y, s = r2.z;
    size_t hoff = (size_t)h * 3;

#pragma unroll
    for (int i = 0; i < 4; ++i) {
        int b = b0 + i;
        const size_t bb = (size_t)b * N_BEADS * 3;
        const float* p1p = p1 + bb + hoff;
        const float* p2p = p2 + bb + hoff;
        const float* Pp  = P  + bb + hoff;
        float a1x = p1p[0], a1y = p1p[1], a1z = p1p[2];
        float a2x = p2p[0], a2y = p2p[1], a2z = p2p[2];

        float cxx = (a1y * a2z - a1z * a2y) * INV_SQRT2;
        float cyy = (a1z * a2x - a1x * a2z) * INV_SQRT2;
        float czz = (a1x * a2y - a1y * a2x) * INV_SQRT2;
        float rx = r1.y * a1x + r1.z * a2x + r1.w * cxx;
        float ry = r1.y * a1y + r1.z * a2y + r1.w * cyy;
        float rz = r1.y * a1z + r1.z * a2z + r1.w * czz;
        float inv = rsqrtf(rx * rx + ry * ry + rz * rz);
        rx *= inv; ry *= inv; rz *= inv;

        // Rodrigues: v' = v + A (r x v) + Bc (r x (r x v)),  v = p1
        float ux = ry * a1z - rz * a1y;
        float uy = rz * a1x - rx * a1z;
        float uz = rx * a1y - ry * a1x;
        float wx = ry * uz - rz * uy;
        float wy = rz * ux - rx * uz;
        float wz = rx * uy - ry * ux;
        float ox = s * (a1x + A * ux + Bc * wx) + Pp[0];
        float oy = s * (a1y + A * uy + Bc * wy) + Pp[1];
        float oz = s * (a1z + A * uz + Bc * wz) + Pp[2];

        union { struct { __half2 lo, hi; } hh; uint2 u; } pk;
        pk.hh.lo = __floats2half2_rn(ox, oy);
        pk.hh.hi = __floats2half2_rn(oz, 0.f);
        cM16[(size_t)b * M + m] = pk.u;
    }
}

// ---------- pass 1b: rot output — one b per block, 2 barriers total ----------
// grid (nchunk, BATCH). Recomputes rot (VALU nearly idle anyway) and does the
// LDS-staged coalesced v4f NONTEMPORAL stores (pure fp32 output).
__global__ void __launch_bounds__(256)
rot_kernel(const float4* __restrict__ rec1,
           const float* __restrict__ p1,
           const float* __restrict__ p2,
           float* __restrict__ out_rot, int M)
{
    int b = blockIdx.y;
    int mbase = blockIdx.x * 256;
    int m = mbase + threadIdx.x;
    __shared__ float sbuf[768];

    float rx = 0.f, ry = 0.f, rz = 0.f;
    if (m < M) {
        float4 r1 = rec1[m];
        int h = __float_as_int(r1.x) >> 4;
        const float* p1p = p1 + ((size_t)b * N_BEADS + h) * 3;
        const float* p2p = p2 + ((size_t)b * N_BEADS + h) * 3;
        float a1x = p1p[0], a1y = p1p[1], a1z = p1p[2];
        float a2x = p2p[0], a2y = p2p[1], a2z = p2p[2];
        float cxx = (a1y * a2z - a1z * a2y) * INV_SQRT2;
        float cyy = (a1z * a2x - a1x * a2z) * INV_SQRT2;
        float czz = (a1x * a2y - a1y * a2x) * INV_SQRT2;
        rx = r1.y * a1x + r1.z * a2x + r1.w * cxx;
        ry = r1.y * a1y + r1.z * a2y + r1.w * cyy;
        rz = r1.y * a1z + r1.z * a2z + r1.w * czz;
        float inv = rsqrtf(rx * rx + ry * ry + rz * rz);
        rx *= inv; ry *= inv; rz *= inv;
    }
    sbuf[threadIdx.x * 3 + 0] = rx;
    sbuf[threadIdx.x * 3 + 1] = ry;
    sbuf[threadIdx.x * 3 + 2] = rz;
    __syncthreads();

    int nm = M - mbase; if (nm > 256) nm = 256;
    int nf = nm * 3;
    size_t base = ((size_t)b * M + mbase) * 3;
    if ((base & 3) == 0) {
        int nf4 = nf >> 2;
        v4f* dst = (v4f*)(out_rot + base);
        if ((int)threadIdx.x < nf4)
            __builtin_nontemporal_store(((const v4f*)sbuf)[threadIdx.x],
                                        &dst[threadIdx.x]);
        int done = nf4 << 2;
        int rem = nf - done;
        if ((int)threadIdx.x < rem)
            __builtin_nontemporal_store(sbuf[done + threadIdx.x],
                                        &out_rot[base + done + threadIdx.x]);
    } else if (m < M) {
        out_rot[base + threadIdx.x * 3 + 0] = rx;
        out_rot[base + threadIdx.x * 3 + 1] = ry;
        out_rot[base + threadIdx.x * 3 + 2] = rz;
    }
}

// ---------- pass 2: sum. One b per block; cM16 b-slice (1.1MB) L2/L3-served;
// csr_m sequential; only random read is cM16[b][m] (8B). Writes every atom
// (no memset), nontemporal. ----------
__global__ void __launch_bounds__(256)
sum2_kernel(const float4* __restrict__ rec_a,
            const int* __restrict__ csr_m,
            const uint2* __restrict__ cM16,
            float* __restrict__ out_atoms, int M, int abps)
{
    int beta = blockIdx.x;
    int xcd  = beta & 7;
    int j    = beta >> 3;
    int round = j / abps;                 // 0..3
    int ablk  = j - round * abps;
    int b = xcd + 8 * round;
    int abase = ablk * 256;
    int a = abase + threadIdx.x;

    float ax = 0.f, ay = 0.f, az = 0.f;
    if (a < N_ATOMS) {
        float4 ra = rec_a[a];
        int cnt = __float_as_int(ra.x);
        int o   = __float_as_int(ra.y);
        const uint2* cb = cM16 + (size_t)b * M;
        for (int k = 0; k < cnt; ++k) {
            int m = csr_m[o + k];
            union { uint2 u; struct { __half2 lo, hi; } hh; } pk;
            pk.u = cb[m];
            float2 xy = __half22float2(pk.hh.lo);
            float2 zp = __half22float2(pk.hh.hi);
            ax += xy.x; ay += xy.y; az += zp.x;
        }
    }
    __shared__ float sbuf[768];
    sbuf[threadIdx.x * 3 + 0] = ax;
    sbuf[threadIdx.x * 3 + 1] = ay;
    sbuf[threadIdx.x * 3 + 2] = az;
    __syncthreads();

    int na = N_ATOMS - abase; if (na > 256) na = 256;
    int nf = na * 3;
    size_t base = ((size_t)b * N_ATOMS + abase) * 3;   // 16B-aligned
    int nf4 = nf >> 2;
    v4f* dst = (v4f*)(out_atoms + base);
    if ((int)threadIdx.x < nf4)
        __builtin_nontemporal_store(((const v4f*)sbuf)[threadIdx.x],
                                    &dst[threadIdx.x]);
    int done = nf4 << 2;
    int rem = nf - done;
    if ((int)threadIdx.x < rem)
        __builtin_nontemporal_store(sbuf[done + threadIdx.x],
                                    &out_atoms[base + done + threadIdx.x]);
}

// ---------- last-resort fallback: atomic scatter ----------
__global__ void __launch_bounds__(256)
backmap_fallback(const float* __restrict__ P, const float* __restrict__ p1,
                 const float* __restrict__ p2, const float* __restrict__ W,
                 const float* __restrict__ ang, const float* __restrict__ scal,
                 const int* __restrict__ slot_idx, const int* __restrict__ atom_idx,
                 float* __restrict__ out_atoms, float* __restrict__ out_rot, int M)
{
    int t = blockIdx.x * blockDim.x + threadIdx.x;
    if (t >= BATCH * M) return;
    int b = t / M; int m = t - b * M;
    int slot = slot_idx[m]; int h = slot >> 4; int l = slot & 15;
    int atom = atom_idx[m];
    const float* p1p = p1 + ((size_t)b * N_BEADS + h) * 3;
    const float* p2p = p2 + ((size_t)b * N_BEADS + h) * 3;
    float a1x = p1p[0], a1y = p1p[1], a1z = p1p[2];
    float a2x = p2p[0], a2y = p2p[1], a2z = p2p[2];
    float cx = (a1y * a2z - a1z * a2y) * INV_SQRT2;
    float cy = (a1z * a2x - a1x * a2z) * INV_SQRT2;
    float cz = (a1x * a2y - a1y * a2x) * INV_SQRT2;
    float w0 = W[(0 * N_BEADS + h) * BEAD_SIZE + l];
    float w1 = W[(1 * N_BEADS + h) * BEAD_SIZE + l];
    float w2 = W[(2 * N_BEADS + h) * BEAD_SIZE + l];
    float rx = w0 * a1x + w1 * a2x + w2 * cx;
    float ry = w0 * a1y + w1 * a2y + w2 * cy;
    float rz = w0 * a1z + w1 * a2z + w2 * cz;
    float inv = rsqrtf(rx * rx + ry * ry + rz * rz);
    rx *= inv; ry *= inv; rz *= inv;
    float* ro = out_rot + (size_t)t * 3;
    ro[0] = rx; ro[1] = ry; ro[2] = rz;
    float sa, ca; __sincosf(ang[m], &sa, &ca);
    float A = 2.f * ca * sa, Bc = 2.f * sa * sa;
    float ux = ry * a1z - rz * a1y;
    float uy = rz * a1x - rx * a1z;
    float uz = rx * a1y - ry * a1x;
    float wx = ry * uz - rz * uy;
    float wy = rz * ux - rx * uz;
    float wz = rx * uy - ry * ux;
    float s = scal[atom];
    const float* Pp = P + ((size_t)b * N_BEADS + h) * 3;
    float* op = out_atoms + ((size_t)b * N_ATOMS + atom) * 3;
    atomicAdd(op + 0, s * (a1x + A * ux + Bc * wx) + Pp[0]);
    atomicAdd(op + 1, s * (a1y + A * uy + Bc * wy) + Pp[1]);
    atomicAdd(op + 2, s * (a1z + A * uz + Bc * wz) + Pp[2]);
}

extern "C" void kernel_launch(void* const* d_in, const int* in_sizes, int n_in,
                              void* d_out, int out_size, void* d_ws, size_t ws_size,
                              hipStream_t stream) {
    const float* P    = (const float*)d_in[0];
    const float* p1   = (const float*)d_in[1];
    const float* p2   = (const float*)d_in[2];
    const float* W    = (const float*)d_in[3];
    const float* ang  = (const float*)d_in[4];
    const float* scal = (const float*)d_in[5];
    const int* slot_idx = (const int*)d_in[6];
    const int* atom_idx = (const int*)d_in[7];

    int M = in_sizes[6];
    float* out_atoms = (float*)d_out;
    float* out_rot   = out_atoms + (size_t)BATCH * N_ATOMS * 3;

    int nblk   = (N_ATOMS + SCAN_BLK - 1) / SCAN_BLK;   // 391
    int nchunk = (M + 255) / 256;                       // 544

    // ws: counts|off|cursor2 (N_ATOMS int) | bsum(512 int)
    //     rec1[M] f4 | recM2[M] f4 | rec_a[N_ATOMS] f4 | csr_m[M] int | cM16[B*M] uint2
    size_t intpre = (size_t)N_ATOMS * 4 * 3 + 512 * 4;   // 16B-aligned
    size_t need   = intpre + (size_t)M * 16 * 2 + (size_t)N_ATOMS * 16
                  + (size_t)M * 4 + (size_t)BATCH * M * 8;

    if (ws_size >= need) {
        int* counts  = (int*)d_ws;
        int* off     = counts + N_ATOMS;
        int* cursor2 = off + N_ATOMS;
        int* bsum    = cursor2 + N_ATOMS;
        float4* rec1  = (float4*)((char*)d_ws + intpre);
        float4* recM2 = rec1 + M;
        float4* rec_a = recM2 + M;
        int*    csr_m = (int*)(rec_a + N_ATOMS);
        uint2*  cM16  = (uint2*)(csr_m + M);             // M*4 % 8 == 0

        zero_kernel<<<nblk, 256, 0, stream>>>(counts, N_ATOMS);
        countrec_kernel<<<nchunk, 256, 0, stream>>>(
            atom_idx, slot_idx, W, ang, scal, counts, rec1, recM2, M);
        scan1_kernel<<<nblk, SCAN_BLK, 0, stream>>>(counts, off, bsum, N_ATOMS);
        scan3_kernel<<<nblk, 256, 0, stream>>>(off, bsum, counts,
                                               cursor2, rec_a, N_ATOMS);
        fill3_kernel<<<nchunk, 256, 0, stream>>>(atom_idx, cursor2, csr_m, M);

        dim3 gc(nchunk, 8);
        contrib16_kernel<<<gc, 256, 0, stream>>>(
            rec1, recM2, p1, p2, P, cM16, M);

        int abps = (N_ATOMS + 255) / 256;                // 391
        sum2_kernel<<<abps * BATCH, 256, 0, stream>>>(
            rec_a, csr_m, cM16, out_atoms, M, abps);

        dim3 gr(nchunk, BATCH);
        rot_kernel<<<gr, 256, 0, stream>>>(rec1, p1, p2, out_rot, M);
        return;
    }

    // last resort: atomic scatter
    hipMemsetAsync(out_atoms, 0, (size_t)BATCH * N_ATOMS * 3 * sizeof(float), stream);
    int total = BATCH * M;
    backmap_fallback<<<(total + 255) / 256, 256, 0, stream>>>(
        P, p1, p2, W, ang, scal, slot_idx, atom_idx,
        out_atoms, out_rot, M);
}

// Round 21
// 86.030 us; speedup vs baseline: 1.1568x; 1.1568x over previous
//
#include <hip/hip_runtime.h>
#include <hip/hip_fp16.h>
#include <math.h>

#define BATCH   32
#define N_BEADS 16384
#define BEAD_SIZE 16
#define N_ATOMS 100000
#define INV_SQRT2 0.70710678118654752440f
#define SCAN_BLK 256

typedef float v4f __attribute__((ext_vector_type(4)));  // native vec for nontemporal

// ---------- zero counts ----------
__global__ void __launch_bounds__(256)
zero_kernel(int* __restrict__ p, int n)
{
    int i = blockIdx.x * 256 + threadIdx.x;
    if (i < n) p[i] = 0;
}

// ---------- countrec: histogram + rec1[m]={slot,w0,w1,w2}
//            + recM2[m]={2cs, 2s^2, scal} (m-order, sequential) ----------
__global__ void __launch_bounds__(256)
countrec_kernel(const int* __restrict__ atom_idx,
                const int* __restrict__ slot_idx,
                const float* __restrict__ W,
                const float* __restrict__ ang,
                const float* __restrict__ scal,
                int* __restrict__ counts,
                float4* __restrict__ rec1,
                float4* __restrict__ recM2, int M)
{
    int m = blockIdx.x * blockDim.x + threadIdx.x;
    if (m >= M) return;
    int a = atom_idx[m];
    atomicAdd(&counts[a], 1);
    int slot = slot_idx[m];
    int h = slot >> 4, l = slot & 15;
    float w0 = W[(0 * N_BEADS + h) * BEAD_SIZE + l];
    float w1 = W[(1 * N_BEADS + h) * BEAD_SIZE + l];
    float w2 = W[(2 * N_BEADS + h) * BEAD_SIZE + l];
    rec1[m] = make_float4(__int_as_float(slot), w0, w1, w2);
    float sa, ca;
    __sincosf(ang[m], &sa, &ca);
    recM2[m] = make_float4(2.f * ca * sa, 2.f * sa * sa, scal[a], 0.f);
}

__global__ void __launch_bounds__(SCAN_BLK)
scan1_kernel(const int* __restrict__ counts, int* __restrict__ off,
             int* __restrict__ bsum, int n)
{
    __shared__ int s[SCAN_BLK];
    int i = blockIdx.x * SCAN_BLK + threadIdx.x;
    int c = (i < n) ? counts[i] : 0;
    s[threadIdx.x] = c;
    __syncthreads();
    int v = c;
    for (int d = 1; d < SCAN_BLK; d <<= 1) {
        int t = (threadIdx.x >= d) ? s[threadIdx.x - d] : 0;
        __syncthreads();
        v += t;
        s[threadIdx.x] = v;
        __syncthreads();
    }
    if (i < n) off[i] = v - c;
    if (threadIdx.x == SCAN_BLK - 1) bsum[blockIdx.x] = v;
}

// finalize offsets; cursor2 seeded with off; rec_a = int2{cnt, off} (8B)
__global__ void __launch_bounds__(256)
scan3_kernel(int* __restrict__ off, const int* __restrict__ bsum,
             const int* __restrict__ counts,
             int* __restrict__ cursor2, int2* __restrict__ rec_a, int n)
{
    __shared__ int red[256];
    int j = blockIdx.x;
    int partial = 0;
    for (int i = threadIdx.x; i < j; i += 256) partial += bsum[i];
    red[threadIdx.x] = partial;
    __syncthreads();
    for (int d = 128; d > 0; d >>= 1) {
        if ((int)threadIdx.x < d) red[threadIdx.x] += red[threadIdx.x + d];
        __syncthreads();
    }
    int bpref = red[0];
    int i = j * 256 + threadIdx.x;
    if (i >= n) return;
    int o = off[i] + bpref;
    off[i] = o;
    cursor2[i] = o;
    rec_a[i] = make_int2(counts[i], o);
}

// fill3: the ONE random scatter — csr_m[pos]=m (cursor2 pre-seeded with off)
__global__ void __launch_bounds__(256)
fill3_kernel(const int* __restrict__ atom_idx,
             int* __restrict__ cursor2, int* __restrict__ csr_m, int M)
{
    int m = blockIdx.x * blockDim.x + threadIdx.x;
    if (m >= M) return;
    int pos = atomicAdd(&cursor2[atom_idx[m]], 1);
    csr_m[pos] = m;
}

// ---------- pass 1: m-order compute (round-14/19 proven body).
// rot (fp32) LDS-staged coalesced v4f NONTEMPORAL stores (pure output);
// cM16 (half4) direct coalesced 8B store (re-read by sum2 -> cached). ----------
__global__ void __launch_bounds__(256)
mcontrib_kernel(const float4* __restrict__ rec1,
                const float4* __restrict__ recM2,
                const float* __restrict__ p1,
                const float* __restrict__ p2,
                const float* __restrict__ P,
                float* __restrict__ out_rot,   // (B, M, 3) fp32
                uint2* __restrict__ cM16,      // (B, M) half4, m-order
                int M)
{
    int bg = blockIdx.y;             // 0..7
    int mbase = blockIdx.x * 256;
    int m = mbase + threadIdx.x;
    int b0 = bg * 4;
    bool act = m < M;
    int mc = act ? m : (M - 1);

    float4 r1 = rec1[mc];
    float4 r2 = recM2[mc];
    int h = __float_as_int(r1.x) >> 4;
    float A = r2.x, Bc = r2.y, s = r2.z;
    size_t hoff = (size_t)h * 3;

    __shared__ float sbuf[768];
    int nm = M - mbase; if (nm > 256) nm = 256;
    int nf = nm * 3;
    int nf4 = nf >> 2;
    int done = nf4 << 2;
    int rem = nf - done;

#pragma unroll
    for (int i = 0; i < 4; ++i) {
        int b = b0 + i;
        const size_t bb = (size_t)b * N_BEADS * 3;
        const float* p1p = p1 + bb + hoff;
        const float* p2p = p2 + bb + hoff;
        const float* Pp  = P  + bb + hoff;
        float a1x = p1p[0], a1y = p1p[1], a1z = p1p[2];
        float a2x = p2p[0], a2y = p2p[1], a2z = p2p[2];

        float cxx = (a1y * a2z - a1z * a2y) * INV_SQRT2;
        float cyy = (a1z * a2x - a1x * a2z) * INV_SQRT2;
        float czz = (a1x * a2y - a1y * a2x) * INV_SQRT2;
        float rx = r1.y * a1x + r1.z * a2x + r1.w * cxx;
        float ry = r1.y * a1y + r1.z * a2y + r1.w * cyy;
        float rz = r1.y * a1z + r1.z * a2z + r1.w * czz;
        float inv = rsqrtf(rx * rx + ry * ry + rz * rz);
        rx *= inv; ry *= inv; rz *= inv;

        // rot output: LDS-staged coalesced v4f nontemporal store
        __syncthreads();
        sbuf[threadIdx.x * 3 + 0] = rx;
        sbuf[threadIdx.x * 3 + 1] = ry;
        sbuf[threadIdx.x * 3 + 2] = rz;
        __syncthreads();
        {
            size_t base = ((size_t)b * M + mbase) * 3;   // 16B-aligned (mbase%256==0)
            v4f* dst = (v4f*)(out_rot + base);
            if ((base & 3) == 0) {
                if ((int)threadIdx.x < nf4)
                    __builtin_nontemporal_store(
                        ((const v4f*)sbuf)[threadIdx.x], &dst[threadIdx.x]);
                if ((int)threadIdx.x < rem)
                    __builtin_nontemporal_store(
                        sbuf[done + threadIdx.x], &out_rot[base + done + threadIdx.x]);
            } else if (act) {
                out_rot[base + threadIdx.x * 3 + 0] = rx;
                out_rot[base + threadIdx.x * 3 + 1] = ry;
                out_rot[base + threadIdx.x * 3 + 2] = rz;
            }
        }

        // Rodrigues contribution: v' = v + A (r x v) + Bc (r x (r x v)), v = p1
        float ux = ry * a1z - rz * a1y;
        float uy = rz * a1x - rx * a1z;
        float uz = rx * a1y - ry * a1x;
        float wx = ry * uz - rz * uy;
        float wy = rz * ux - rx * uz;
        float wz = rx * uy - ry * ux;
        float ox = s * (a1x + A * ux + Bc * wx) + Pp[0];
        float oy = s * (a1y + A * uy + Bc * wy) + Pp[1];
        float oz = s * (a1z + A * uz + Bc * wz) + Pp[2];

        // contribution: half4 pack, SEQUENTIAL m-order 8B store (coalesced, cached)
        if (act) {
            union { struct { __half2 lo, hi; } hh; uint2 u; } pk;
            pk.hh.lo = __floats2half2_rn(ox, oy);
            pk.hh.hi = __floats2half2_rn(oz, 0.f);
            cM16[(size_t)b * M + m] = pk.u;
        }
    }
}

// ---------- pass 2: sum. One b per block; cM16 b-slice (1.1MB) L2-resident
// on its XCD (b = xcd + 8*round). csr_m sequential; only random read is
// cM16[b][m] (8B). Writes every atom (no memset), nontemporal. ----------
__global__ void __launch_bounds__(256)
sum2_kernel(const int2* __restrict__ rec_a,
            const int* __restrict__ csr_m,
            const uint2* __restrict__ cM16,
            float* __restrict__ out_atoms, int M, int abps)
{
    int beta = blockIdx.x;
    int xcd  = beta & 7;
    int j    = beta >> 3;
    int round = j / abps;                 // 0..3
    int ablk  = j - round * abps;
    int b = xcd + 8 * round;
    int abase = ablk * 256;
    int a = abase + threadIdx.x;

    float ax = 0.f, ay = 0.f, az = 0.f;
    if (a < N_ATOMS) {
        int2 ra = rec_a[a];
        int cnt = ra.x;
        int o   = ra.y;
        const uint2* cb = cM16 + (size_t)b * M;
        for (int k = 0; k < cnt; ++k) {
            int m = csr_m[o + k];
            union { uint2 u; struct { __half2 lo, hi; } hh; } pk;
            pk.u = cb[m];
            float2 xy = __half22float2(pk.hh.lo);
            float2 zp = __half22float2(pk.hh.hi);
            ax += xy.x; ay += xy.y; az += zp.x;
        }
    }
    __shared__ float sbuf[768];
    sbuf[threadIdx.x * 3 + 0] = ax;
    sbuf[threadIdx.x * 3 + 1] = ay;
    sbuf[threadIdx.x * 3 + 2] = az;
    __syncthreads();

    int na = N_ATOMS - abase; if (na > 256) na = 256;
    int nf = na * 3;
    size_t base = ((size_t)b * N_ATOMS + abase) * 3;   // 16B-aligned
    int nf4 = nf >> 2;
    v4f* dst = (v4f*)(out_atoms + base);
    if ((int)threadIdx.x < nf4)
        __builtin_nontemporal_store(((const v4f*)sbuf)[threadIdx.x],
                                    &dst[threadIdx.x]);
    int done = nf4 << 2;
    int rem = nf - done;
    if ((int)threadIdx.x < rem)
        __builtin_nontemporal_store(sbuf[done + threadIdx.x],
                                    &out_atoms[base + done + threadIdx.x]);
}

// ---------- last-resort fallback: atomic scatter ----------
__global__ void __launch_bounds__(256)
backmap_fallback(const float* __restrict__ P, const float* __restrict__ p1,
                 const float* __restrict__ p2, const float* __restrict__ W,
                 const float* __restrict__ ang, const float* __restrict__ scal,
                 const int* __restrict__ slot_idx, const int* __restrict__ atom_idx,
                 float* __restrict__ out_atoms, float* __restrict__ out_rot, int M)
{
    int t = blockIdx.x * blockDim.x + threadIdx.x;
    if (t >= BATCH * M) return;
    int b = t / M; int m = t - b * M;
    int slot = slot_idx[m]; int h = slot >> 4; int l = slot & 15;
    int atom = atom_idx[m];
    const float* p1p = p1 + ((size_t)b * N_BEADS + h) * 3;
    const float* p2p = p2 + ((size_t)b * N_BEADS + h) * 3;
    float a1x = p1p[0], a1y = p1p[1], a1z = p1p[2];
    float a2x = p2p[0], a2y = p2p[1], a2z = p2p[2];
    float cx = (a1y * a2z - a1z * a2y) * INV_SQRT2;
    float cy = (a1z * a2x - a1x * a2z) * INV_SQRT2;
    float cz = (a1x * a2y - a1y * a2x) * INV_SQRT2;
    float w0 = W[(0 * N_BEADS + h) * BEAD_SIZE + l];
    float w1 = W[(1 * N_BEADS + h) * BEAD_SIZE + l];
    float w2 = W[(2 * N_BEADS + h) * BEAD_SIZE + l];
    float rx = w0 * a1x + w1 * a2x + w2 * cx;
    float ry = w0 * a1y + w1 * a2y + w2 * cy;
    float rz = w0 * a1z + w1 * a2z + w2 * cz;
    float inv = rsqrtf(rx * rx + ry * ry + rz * rz);
    rx *= inv; ry *= inv; rz *= inv;
    float* ro = out_rot + (size_t)t * 3;
    ro[0] = rx; ro[1] = ry; ro[2] = rz;
    float sa, ca; __sincosf(ang[m], &sa, &ca);
    float A = 2.f * ca * sa, Bc = 2.f * sa * sa;
    float ux = ry * a1z - rz * a1y;
    float uy = rz * a1x - rx * a1z;
    float uz = rx * a1y - ry * a1x;
    float wx = ry * uz - rz * uy;
    float wy = rz * ux - rx * uz;
    float wz = rx * uy - ry * ux;
    float s = scal[atom];
    const float* Pp = P + ((size_t)b * N_BEADS + h) * 3;
    float* op = out_atoms + ((size_t)b * N_ATOMS + atom) * 3;
    atomicAdd(op + 0, s * (a1x + A * ux + Bc * wx) + Pp[0]);
    atomicAdd(op + 1, s * (a1y + A * uy + Bc * wy) + Pp[1]);
    atomicAdd(op + 2, s * (a1z + A * uz + Bc * wz) + Pp[2]);
}

extern "C" void kernel_launch(void* const* d_in, const int* in_sizes, int n_in,
                              void* d_out, int out_size, void* d_ws, size_t ws_size,
                              hipStream_t stream) {
    const float* P    = (const float*)d_in[0];
    const float* p1   = (const float*)d_in[1];
    const float* p2   = (const float*)d_in[2];
    const float* W    = (const float*)d_in[3];
    const float* ang  = (const float*)d_in[4];
    const float* scal = (const float*)d_in[5];
    const int* slot_idx = (const int*)d_in[6];
    const int* atom_idx = (const int*)d_in[7];

    int M = in_sizes[6];
    float* out_atoms = (float*)d_out;
    float* out_rot   = out_atoms + (size_t)BATCH * N_ATOMS * 3;

    int nblk   = (N_ATOMS + SCAN_BLK - 1) / SCAN_BLK;   // 391
    int nchunk = (M + 255) / 256;                       // 544

    // ws: counts|off|cursor2 (N_ATOMS int) | bsum(512 int)
    //     rec1[M] f4 | recM2[M] f4 | rec_a[N_ATOMS] int2 | csr_m[M] int | cM16[B*M] uint2
    size_t intpre = (size_t)N_ATOMS * 4 * 3 + 512 * 4;   // 16B-aligned
    size_t need   = intpre + (size_t)M * 16 * 2 + (size_t)N_ATOMS * 8
                  + (size_t)M * 4 + (size_t)BATCH * M * 8;

    if (ws_size >= need) {
        int* counts  = (int*)d_ws;
        int* off     = counts + N_ATOMS;
        int* cursor2 = off + N_ATOMS;
        int* bsum    = cursor2 + N_ATOMS;
        float4* rec1  = (float4*)((char*)d_ws + intpre);
        float4* recM2 = rec1 + M;
        int2*   rec_a = (int2*)(recM2 + M);
        int*    csr_m = (int*)(rec_a + N_ATOMS);
        uint2*  cM16  = (uint2*)(csr_m + M);             // M*4 % 8 == 0

        zero_kernel<<<nblk, 256, 0, stream>>>(counts, N_ATOMS);
        countrec_kernel<<<nchunk, 256, 0, stream>>>(
            atom_idx, slot_idx, W, ang, scal, counts, rec1, recM2, M);
        scan1_kernel<<<nblk, SCAN_BLK, 0, stream>>>(counts, off, bsum, N_ATOMS);
        scan3_kernel<<<nblk, 256, 0, stream>>>(off, bsum, counts,
                                               cursor2, rec_a, N_ATOMS);
        fill3_kernel<<<nchunk, 256, 0, stream>>>(atom_idx, cursor2, csr_m, M);

        dim3 gm(nchunk, 8);
        mcontrib_kernel<<<gm, 256, 0, stream>>>(
            rec1, recM2, p1, p2, P, out_rot, cM16, M);

        int abps = (N_ATOMS + 255) / 256;                // 391
        sum2_kernel<<<abps * BATCH, 256, 0, stream>>>(
            rec_a, csr_m, cM16, out_atoms, M, abps);
        return;
    }

    // last resort: atomic scatter
    hipMemsetAsync(out_atoms, 0, (size_t)BATCH * N_ATOMS * 3 * sizeof(float), stream);
    int total = BATCH * M;
    backmap_fallback<<<(total + 255) / 256, 256, 0, stream>>>(
        P, p1, p2, W, ang, scal, slot_idx, atom_idx,
        out_atoms, out_rot, M);
}

// Round 22
// 85.540 us; speedup vs baseline: 1.1634x; 1.0057x over previous
//
#include <hip/hip_runtime.h>
#include <hip/hip_fp16.h>
#include <math.h>

#define BATCH   32
#define N_BEADS 16384
#define BEAD_SIZE 16
#define N_ATOMS 100000
#define INV_SQRT2 0.70710678118654752440f
#define SCAN_BLK 256

typedef float v4f __attribute__((ext_vector_type(4)));  // native vec for nontemporal

// ---------- zero counts ----------
__global__ void __launch_bounds__(256)
zero_kernel(int* __restrict__ p, int n)
{
    int i = blockIdx.x * 256 + threadIdx.x;
    if (i < n) p[i] = 0;
}

// ---------- countrec: histogram + recC[m] = {slot, (w0,w1)h2, (w2,A)h2, (B,scal)h2}
//            single 16B m-order record (halves mcontrib's rec stream) ----------
__global__ void __launch_bounds__(256)
countrec_kernel(const int* __restrict__ atom_idx,
                const int* __restrict__ slot_idx,
                const float* __restrict__ W,
                const float* __restrict__ ang,
                const float* __restrict__ scal,
                int* __restrict__ counts,
                uint4* __restrict__ recC, int M)
{
    int m = blockIdx.x * blockDim.x + threadIdx.x;
    if (m >= M) return;
    int a = atom_idx[m];
    atomicAdd(&counts[a], 1);
    int slot = slot_idx[m];
    int h = slot >> 4, l = slot & 15;
    float w0 = W[(0 * N_BEADS + h) * BEAD_SIZE + l];
    float w1 = W[(1 * N_BEADS + h) * BEAD_SIZE + l];
    float w2 = W[(2 * N_BEADS + h) * BEAD_SIZE + l];
    float sa, ca;
    __sincosf(ang[m], &sa, &ca);
    float A = 2.f * ca * sa, Bc = 2.f * sa * sa;

    union { __half2 h2; unsigned u; } pk01, pk2A, pkBs;
    pk01.h2 = __floats2half2_rn(w0, w1);
    pk2A.h2 = __floats2half2_rn(w2, A);
    pkBs.h2 = __floats2half2_rn(Bc, scal[a]);
    recC[m] = make_uint4((unsigned)slot, pk01.u, pk2A.u, pkBs.u);
}

__global__ void __launch_bounds__(SCAN_BLK)
scan1_kernel(const int* __restrict__ counts, int* __restrict__ off,
             int* __restrict__ bsum, int n)
{
    __shared__ int s[SCAN_BLK];
    int i = blockIdx.x * SCAN_BLK + threadIdx.x;
    int c = (i < n) ? counts[i] : 0;
    s[threadIdx.x] = c;
    __syncthreads();
    int v = c;
    for (int d = 1; d < SCAN_BLK; d <<= 1) {
        int t = (threadIdx.x >= d) ? s[threadIdx.x - d] : 0;
        __syncthreads();
        v += t;
        s[threadIdx.x] = v;
        __syncthreads();
    }
    if (i < n) off[i] = v - c;
    if (threadIdx.x == SCAN_BLK - 1) bsum[blockIdx.x] = v;
}

// finalize offsets; cursor2 seeded with off; rec_a = int2{cnt, off} (8B)
__global__ void __launch_bounds__(256)
scan3_kernel(int* __restrict__ off, const int* __restrict__ bsum,
             const int* __restrict__ counts,
             int* __restrict__ cursor2, int2* __restrict__ rec_a, int n)
{
    __shared__ int red[256];
    int j = blockIdx.x;
    int partial = 0;
    for (int i = threadIdx.x; i < j; i += 256) partial += bsum[i];
    red[threadIdx.x] = partial;
    __syncthreads();
    for (int d = 128; d > 0; d >>= 1) {
        if ((int)threadIdx.x < d) red[threadIdx.x] += red[threadIdx.x + d];
        __syncthreads();
    }
    int bpref = red[0];
    int i = j * 256 + threadIdx.x;
    if (i >= n) return;
    int o = off[i] + bpref;
    off[i] = o;
    cursor2[i] = o;
    rec_a[i] = make_int2(counts[i], o);
}

// fill3: the ONE random scatter — csr_m[pos]=m (cursor2 pre-seeded with off)
__global__ void __launch_bounds__(256)
fill3_kernel(const int* __restrict__ atom_idx,
             int* __restrict__ cursor2, int* __restrict__ csr_m, int M)
{
    int m = blockIdx.x * blockDim.x + threadIdx.x;
    if (m >= M) return;
    int pos = atomicAdd(&cursor2[atom_idx[m]], 1);
    csr_m[pos] = m;
}

// ---------- pass 1: m-order compute (round-19 proven body, single 16B rec).
// rot (fp32) LDS-staged coalesced v4f NONTEMPORAL stores (pure output);
// cM16 (half4) direct coalesced 8B store (re-read by sum2 -> cached). ----------
__global__ void __launch_bounds__(256)
mcontrib_kernel(const uint4* __restrict__ recC,
                const float* __restrict__ p1,
                const float* __restrict__ p2,
                const float* __restrict__ P,
                float* __restrict__ out_rot,   // (B, M, 3) fp32
                uint2* __restrict__ cM16,      // (B, M) half4, m-order
                int M)
{
    int bg = blockIdx.y;             // 0..7
    int mbase = blockIdx.x * 256;
    int m = mbase + threadIdx.x;
    int b0 = bg * 4;
    bool act = m < M;
    int mc = act ? m : (M - 1);

    uint4 rc = recC[mc];
    int h = (int)rc.x >> 4;
    union { unsigned u; __half2 h2; } u01, u2A, uBs;
    u01.u = rc.y; u2A.u = rc.z; uBs.u = rc.w;
    float2 f01 = __half22float2(u01.h2);
    float2 f2A = __half22float2(u2A.h2);
    float2 fBs = __half22float2(uBs.h2);
    float w0 = f01.x, w1 = f01.y, w2 = f2A.x;
    float A = f2A.y, Bc = fBs.x, s = fBs.y;
    size_t hoff = (size_t)h * 3;

    __shared__ float sbuf[768];
    int nm = M - mbase; if (nm > 256) nm = 256;
    int nf = nm * 3;
    int nf4 = nf >> 2;
    int done = nf4 << 2;
    int rem = nf - done;

#pragma unroll
    for (int i = 0; i < 4; ++i) {
        int b = b0 + i;
        const size_t bb = (size_t)b * N_BEADS * 3;
        const float* p1p = p1 + bb + hoff;
        const float* p2p = p2 + bb + hoff;
        const float* Pp  = P  + bb + hoff;
        float a1x = p1p[0], a1y = p1p[1], a1z = p1p[2];
        float a2x = p2p[0], a2y = p2p[1], a2z = p2p[2];

        float cxx = (a1y * a2z - a1z * a2y) * INV_SQRT2;
        float cyy = (a1z * a2x - a1x * a2z) * INV_SQRT2;
        float czz = (a1x * a2y - a1y * a2x) * INV_SQRT2;
        float rx = w0 * a1x + w1 * a2x + w2 * cxx;
        float ry = w0 * a1y + w1 * a2y + w2 * cyy;
        float rz = w0 * a1z + w1 * a2z + w2 * czz;
        float inv = rsqrtf(rx * rx + ry * ry + rz * rz);
        rx *= inv; ry *= inv; rz *= inv;

        // rot output: LDS-staged coalesced v4f nontemporal store
        __syncthreads();
        sbuf[threadIdx.x * 3 + 0] = rx;
        sbuf[threadIdx.x * 3 + 1] = ry;
        sbuf[threadIdx.x * 3 + 2] = rz;
        __syncthreads();
        {
            size_t base = ((size_t)b * M + mbase) * 3;   // mbase%256==0 -> 16B-aligned
            v4f* dst = (v4f*)(out_rot + base);
            if ((base & 3) == 0) {
                if ((int)threadIdx.x < nf4)
                    __builtin_nontemporal_store(
                        ((const v4f*)sbuf)[threadIdx.x], &dst[threadIdx.x]);
                if ((int)threadIdx.x < rem)
                    __builtin_nontemporal_store(
                        sbuf[done + threadIdx.x], &out_rot[base + done + threadIdx.x]);
            } else if (act) {
                out_rot[base + threadIdx.x * 3 + 0] = rx;
                out_rot[base + threadIdx.x * 3 + 1] = ry;
                out_rot[base + threadIdx.x * 3 + 2] = rz;
            }
        }

        // Rodrigues contribution: v' = v + A (r x v) + Bc (r x (r x v)), v = p1
        float ux = ry * a1z - rz * a1y;
        float uy = rz * a1x - rx * a1z;
        float uz = rx * a1y - ry * a1x;
        float wx = ry * uz - rz * uy;
        float wy = rz * ux - rx * uz;
        float wz = rx * uy - ry * ux;
        float ox = s * (a1x + A * ux + Bc * wx) + Pp[0];
        float oy = s * (a1y + A * uy + Bc * wy) + Pp[1];
        float oz = s * (a1z + A * uz + Bc * wz) + Pp[2];

        // contribution: half4 pack, SEQUENTIAL m-order 8B store (coalesced, cached)
        if (act) {
            union { struct { __half2 lo, hi; } hh; uint2 u; } pk;
            pk.hh.lo = __floats2half2_rn(ox, oy);
            pk.hh.hi = __floats2half2_rn(oz, 0.f);
            cM16[(size_t)b * M + m] = pk.u;
        }
    }
}

// ---------- pass 2: sum. One b per block; cM16 b-slice (1.1MB) L2-resident
// on its XCD (b = xcd + 8*round). csr_m sequential; only random read is
// cM16[b][m] (8B). Writes every atom (no memset), nontemporal. ----------
__global__ void __launch_bounds__(256)
sum2_kernel(const int2* __restrict__ rec_a,
            const int* __restrict__ csr_m,
            const uint2* __restrict__ cM16,
            float* __restrict__ out_atoms, int M, int abps)
{
    int beta = blockIdx.x;
    int xcd  = beta & 7;
    int j    = beta >> 3;
    int round = j / abps;                 // 0..3
    int ablk  = j - round * abps;
    int b = xcd + 8 * round;
    int abase = ablk * 256;
    int a = abase + threadIdx.x;

    float ax = 0.f, ay = 0.f, az = 0.f;
    if (a < N_ATOMS) {
        int2 ra = rec_a[a];
        int cnt = ra.x;
        int o   = ra.y;
        const uint2* cb = cM16 + (size_t)b * M;
        for (int k = 0; k < cnt; ++k) {
            int m = csr_m[o + k];
            union { uint2 u; struct { __half2 lo, hi; } hh; } pk;
            pk.u = cb[m];
            float2 xy = __half22float2(pk.hh.lo);
            float2 zp = __half22float2(pk.hh.hi);
            ax += xy.x; ay += xy.y; az += zp.x;
        }
    }
    __shared__ float sbuf[768];
    sbuf[threadIdx.x * 3 + 0] = ax;
    sbuf[threadIdx.x * 3 + 1] = ay;
    sbuf[threadIdx.x * 3 + 2] = az;
    __syncthreads();

    int na = N_ATOMS - abase; if (na > 256) na = 256;
    int nf = na * 3;
    size_t base = ((size_t)b * N_ATOMS + abase) * 3;   // 16B-aligned
    int nf4 = nf >> 2;
    v4f* dst = (v4f*)(out_atoms + base);
    if ((int)threadIdx.x < nf4)
        __builtin_nontemporal_store(((const v4f*)sbuf)[threadIdx.x],
                                    &dst[threadIdx.x]);
    int done = nf4 << 2;
    int rem = nf - done;
    if ((int)threadIdx.x < rem)
        __builtin_nontemporal_store(sbuf[done + threadIdx.x],
                                    &out_atoms[base + done + threadIdx.x]);
}

// ---------- last-resort fallback: atomic scatter ----------
__global__ void __launch_bounds__(256)
backmap_fallback(const float* __restrict__ P, const float* __restrict__ p1,
                 const float* __restrict__ p2, const float* __restrict__ W,
                 const float* __restrict__ ang, const float* __restrict__ scal,
                 const int* __restrict__ slot_idx, const int* __restrict__ atom_idx,
                 float* __restrict__ out_atoms, float* __restrict__ out_rot, int M)
{
    int t = blockIdx.x * blockDim.x + threadIdx.x;
    if (t >= BATCH * M) return;
    int b = t / M; int m = t - b * M;
    int slot = slot_idx[m]; int h = slot >> 4; int l = slot & 15;
    int atom = atom_idx[m];
    const float* p1p = p1 + ((size_t)b * N_BEADS + h) * 3;
    const float* p2p = p2 + ((size_t)b * N_BEADS + h) * 3;
    float a1x = p1p[0], a1y = p1p[1], a1z = p1p[2];
    float a2x = p2p[0], a2y = p2p[1], a2z = p2p[2];
    float cx = (a1y * a2z - a1z * a2y) * INV_SQRT2;
    float cy = (a1z * a2x - a1x * a2z) * INV_SQRT2;
    float cz = (a1x * a2y - a1y * a2x) * INV_SQRT2;
    float w0 = W[(0 * N_BEADS + h) * BEAD_SIZE + l];
    float w1 = W[(1 * N_BEADS + h) * BEAD_SIZE + l];
    float w2 = W[(2 * N_BEADS + h) * BEAD_SIZE + l];
    float rx = w0 * a1x + w1 * a2x + w2 * cx;
    float ry = w0 * a1y + w1 * a2y + w2 * cy;
    float rz = w0 * a1z + w1 * a2z + w2 * cz;
    float inv = rsqrtf(rx * rx + ry * ry + rz * rz);
    rx *= inv; ry *= inv; rz *= inv;
    float* ro = out_rot + (size_t)t * 3;
    ro[0] = rx; ro[1] = ry; ro[2] = rz;
    float sa, ca; __sincosf(ang[m], &sa, &ca);
    float A = 2.f * ca * sa, Bc = 2.f * sa * sa;
    float ux = ry * a1z - rz * a1y;
    float uy = rz * a1x - rx * a1z;
    float uz = rx * a1y - ry * a1x;
    float wx = ry * uz - rz * uy;
    float wy = rz * ux - rx * uz;
    float wz = rx * uy - ry * ux;
    float s = scal[atom];
    const float* Pp = P + ((size_t)b * N_BEADS + h) * 3;
    float* op = out_atoms + ((size_t)b * N_ATOMS + atom) * 3;
    atomicAdd(op + 0, s * (a1x + A * ux + Bc * wx) + Pp[0]);
    atomicAdd(op + 1, s * (a1y + A * uy + Bc * wy) + Pp[1]);
    atomicAdd(op + 2, s * (a1z + A * uz + Bc * wz) + Pp[2]);
}

extern "C" void kernel_launch(void* const* d_in, const int* in_sizes, int n_in,
                              void* d_out, int out_size, void* d_ws, size_t ws_size,
                              hipStream_t stream) {
    const float* P    = (const float*)d_in[0];
    const float* p1   = (const float*)d_in[1];
    const float* p2   = (const float*)d_in[2];
    const float* W    = (const float*)d_in[3];
    const float* ang  = (const float*)d_in[4];
    const float* scal = (const float*)d_in[5];
    const int* slot_idx = (const int*)d_in[6];
    const int* atom_idx = (const int*)d_in[7];

    int M = in_sizes[6];
    float* out_atoms = (float*)d_out;
    float* out_rot   = out_atoms + (size_t)BATCH * N_ATOMS * 3;

    int nblk   = (N_ATOMS + SCAN_BLK - 1) / SCAN_BLK;   // 391
    int nchunk = (M + 255) / 256;                       // 544

    // ws: counts|off|cursor2 (N_ATOMS int) | bsum(512 int)
    //     recC[M] u4 | rec_a[N_ATOMS] int2 | csr_m[M] int | cM16[B*M] uint2
    size_t intpre = (size_t)N_ATOMS * 4 * 3 + 512 * 4;   // 16B-aligned
    size_t need   = intpre + (size_t)M * 16 + (size_t)N_ATOMS * 8
                  + (size_t)M * 4 + (size_t)BATCH * M * 8;

    if (ws_size >= need) {
        int* counts  = (int*)d_ws;
        int* off     = counts + N_ATOMS;
        int* cursor2 = off + N_ATOMS;
        int* bsum    = cursor2 + N_ATOMS;
        uint4* recC  = (uint4*)((char*)d_ws + intpre);
        int2*  rec_a = (int2*)(recC + M);
        int*   csr_m = (int*)(rec_a + N_ATOMS);
        uint2* cM16  = (uint2*)(csr_m + M);              // M*4 % 8 == 0

        zero_kernel<<<nblk, 256, 0, stream>>>(counts, N_ATOMS);
        countrec_kernel<<<nchunk, 256, 0, stream>>>(
            atom_idx, slot_idx, W, ang, scal, counts, recC, M);
        scan1_kernel<<<nblk, SCAN_BLK, 0, stream>>>(counts, off, bsum, N_ATOMS);
        scan3_kernel<<<nblk, 256, 0, stream>>>(off, bsum, counts,
                                               cursor2, rec_a, N_ATOMS);
        fill3_kernel<<<nchunk, 256, 0, stream>>>(atom_idx, cursor2, csr_m, M);

        dim3 gm(nchunk, 8);
        mcontrib_kernel<<<gm, 256, 0, stream>>>(
            recC, p1, p2, P, out_rot, cM16, M);

        int abps = (N_ATOMS + 255) / 256;                // 391
        sum2_kernel<<<abps * BATCH, 256, 0, stream>>>(
            rec_a, csr_m, cM16, out_atoms, M, abps);
        return;
    }

    // last resort: atomic scatter
    hipMemsetAsync(out_atoms, 0, (size_t)BATCH * N_ATOMS * 3 * sizeof(float), stream);
    int total = BATCH * M;
    backmap_fallback<<<(total + 255) / 256, 256, 0, stream>>>(
        P, p1, p2, W, ang, scal, slot_idx, atom_idx,
        out_atoms, out_rot, M);
}